// Round 11
// baseline (796.431 us; speedup 1.0000x reference)
//
#include <hip/hip_runtime.h>

#define N_NODES 4096
#define F_UAV 64
#define NOBS 262400
#define GCN_FLAT (N_NODES * F_UAV)   // 262144
#define HDIM 1024
#define N_ACT 64
#define N_EDGES 65536
#define NBLK 512

typedef float f32x4 __attribute__((ext_vector_type(4)));

// ---- workspace layout (4-byte units) ----
#define OFF_BAR   0                            // 2 ints (count, gen)
#define OFF_CNT   2                            // 4096 ints (degree/bucket cursor)
#define OFF_SSRC  (OFF_CNT + N_NODES)          // 4096*64 ints
#define OFF_H     (OFF_SSRC + N_NODES * 64)    // 262144 floats
#define OFF_P1    (OFF_H + GCN_FLAT)           // 512*1024 floats
#define OFF_Q1T   (OFF_P1 + NBLK * HDIM)       // 1024*64 floats
#define OFF_P2    (OFF_Q1T + HDIM * 64)        // 64*1024 floats

// sense-reversing device-scope grid barrier (all NBLK blocks participate)
__device__ __forceinline__ void gbar(int* bar) {
    __syncthreads();
    __threadfence();
    if (threadIdx.x == 0) {
        int* cnt = bar;
        int* gen = bar + 1;
        int g = __hip_atomic_load(gen, __ATOMIC_ACQUIRE, __HIP_MEMORY_SCOPE_AGENT);
        int a = __hip_atomic_fetch_add(cnt, 1, __ATOMIC_ACQ_REL, __HIP_MEMORY_SCOPE_AGENT);
        if (a == NBLK - 1) {
            __hip_atomic_store(cnt, 0, __ATOMIC_RELAXED, __HIP_MEMORY_SCOPE_AGENT);
            __hip_atomic_fetch_add(gen, 1, __ATOMIC_ACQ_REL, __HIP_MEMORY_SCOPE_AGENT);
        } else {
            while (__hip_atomic_load(gen, __ATOMIC_ACQUIRE, __HIP_MEMORY_SCOPE_AGENT) == g)
                __builtin_amdgcn_s_sleep(4);
        }
    }
    __syncthreads();
    __threadfence();
}

__global__ __launch_bounds__(256, 4)
void k_fused(const float* __restrict__ nx, const float* __restrict__ obs,
             const float* __restrict__ gw, const float* __restrict__ gb,
             const float* __restrict__ w1, const float* __restrict__ b1,
             const float* __restrict__ w2, const float* __restrict__ b2,
             const float* __restrict__ wv, const float* __restrict__ bv,
             const float* __restrict__ wa, const float* __restrict__ ba,
             const int* __restrict__ src, const int* __restrict__ dst,
             int* __restrict__ wsi, float* __restrict__ out) {
    int tid = threadIdx.x, b = blockIdx.x;
    int* bar  = wsi + OFF_BAR;
    int* cnt  = wsi + OFF_CNT;
    int* ssrc = wsi + OFF_SSRC;
    float* h   = (float*)wsi + OFF_H;
    float* p1  = (float*)wsi + OFF_P1;
    float* q1T = (float*)wsi + OFF_Q1T;
    float* p2  = (float*)wsi + OFF_P2;

    __shared__ float sw[F_UAV * F_UAV];   // 16 KB
    __shared__ float snx[512];
    __shared__ float sx[513];

    // ---- P1: h = node_x @ gcn_w for nodes [8b, 8b+8) + bucket-place 128 edges
    for (int i = tid; i < F_UAV * F_UAV; i += 256) sw[i] = gw[i];
    snx[tid]       = nx[b * 512 + tid];
    snx[256 + tid] = nx[b * 512 + 256 + tid];
    __syncthreads();
    {
        int r = tid >> 6, j = tid & 63;
#pragma unroll
        for (int half = 0; half < 2; ++half) {
            float acc = 0.f;
#pragma unroll
            for (int k = 0; k < 64; ++k) acc += snx[half * 256 + r * 64 + k] * sw[k * 64 + j];
            h[b * 512 + half * 256 + r * 64 + j] = acc;
        }
    }
    if (tid < 128) {
        int e = b * 128 + tid;
        int d = dst[e];
        int slot = atomicAdd(&cnt[d], 1);
        if (slot < 64) ssrc[d * 64 + slot] = src[e];
    }
    gbar(bar);

    // ---- P2: gather own x (8 nodes; wave w -> nodes 8b+2w, 8b+2w+1), then mv1
    {
        int w = tid >> 6, l = tid & 63;
#pragma unroll
        for (int q = 0; q < 2; ++q) {
            int n = b * 8 + w * 2 + q;
            int dn = cnt[n];
            int dm = dn < 64 ? dn : 64;
            float a0 = 0.f;
            for (int i = 0; i < dm; ++i) {
                int s = ssrc[n * 64 + i];
                a0 += h[s * 64 + l] * rsqrtf((float)(cnt[s] + 1));
            }
            float di = rsqrtf((float)(dn + 1));
            sx[(w * 2 + q) * 64 + l] = di * a0 + di * di * h[n * 64 + l] + gb[l];
        }
        if (tid == 0) sx[512] = (b < 256) ? obs[GCN_FLAT + b] : 0.f;
    }
    __syncthreads();
    {
        f32x4 acc = {0.f, 0.f, 0.f, 0.f};
        const f32x4* Wr = (const f32x4*)w1 + (size_t)(b * 512) * (HDIM / 4) + tid;
        for (int k = 0; k < 512; k += 8) {
#pragma unroll
            for (int u = 0; u < 8; ++u)
                acc += sx[k + u] * __builtin_nontemporal_load(&Wr[(size_t)(k + u) * (HDIM / 4)]);
        }
        if (b < 256) {
            const f32x4* wt = (const f32x4*)w1 + (size_t)(GCN_FLAT + b) * (HDIM / 4) + tid;
            acc += sx[512] * __builtin_nontemporal_load(wt);
        }
        ((f32x4*)(p1 + (size_t)b * HDIM))[tid] = acc;
    }
    gbar(bar);

    // ---- P3: 64 blocks: sum 8 p1 rows -> q1T transposed [1024][64]
    if (b < 64) {
        const f32x4* p = (const f32x4*)p1 + (size_t)b * 8 * (HDIM / 4) + tid;
        f32x4 a4 = {0.f, 0.f, 0.f, 0.f};
#pragma unroll
        for (int r8 = 0; r8 < 8; ++r8) a4 += p[(size_t)r8 * (HDIM / 4)];
#pragma unroll
        for (int u = 0; u < 4; ++u) q1T[(size_t)(4 * tid + u) * 64 + b] = a4[u];
    }
    gbar(bar);

    // ---- P4: 64 blocks: y1 rows [16b,16b+16) = relu(b1 + rowsum), matvec vs w2
    if (b < 64) {
        __shared__ float s_y[16];
        int w = tid >> 6, l = tid & 63;
#pragma unroll
        for (int rr = 0; rr < 4; ++rr) {
            int jj = 16 * b + 4 * w + rr;
            float sm = q1T[(size_t)jj * 64 + l];
            for (int off = 32; off; off >>= 1) sm += __shfl_xor(sm, off);
            if (l == 0) s_y[4 * w + rr] = fmaxf(b1[jj] + sm, 0.f);
        }
        __syncthreads();
        f32x4 a4 = {0.f, 0.f, 0.f, 0.f};
        const f32x4* Wr = (const f32x4*)w2 + (size_t)(16 * b) * (HDIM / 4) + tid;
#pragma unroll
        for (int i = 0; i < 16; ++i) a4 += s_y[i] * Wr[(size_t)i * (HDIM / 4)];
        ((f32x4*)(p2 + (size_t)b * HDIM))[tid] = a4;
    }
    gbar(bar);

    // ---- P5: block 0: y2 = relu(b2 + colsum p2) + dueling heads
    if (b == 0) {
        __shared__ float y2s[HDIM];
        __shared__ float spv[256];
        __shared__ float sadv[4][64];
        float pv = 0.f;
#pragma unroll
        for (int i = 0; i < 4; ++i) {
            int jj = tid + 256 * i;
            float a = b2[jj];
            for (int s = 0; s < 64; ++s) a += p2[(size_t)s * HDIM + jj];
            float y = fmaxf(a, 0.f);
            y2s[jj] = y;
            pv += y * wv[jj];
        }
        spv[tid] = pv;
        __syncthreads();
        int gg = tid >> 6, a_ = tid & 63;
        float pa = 0.f;
        for (int k = 0; k < 256; ++k) {
            int kk = gg * 256 + k;
            pa += y2s[kk] * wa[kk * 64 + a_];
        }
        sadv[gg][a_] = pa;
        __syncthreads();
        if (tid < 64) {
            float adv = ba[a_] + sadv[0][a_] + sadv[1][a_] + sadv[2][a_] + sadv[3][a_];
            float v = spv[a_] + spv[a_ + 64] + spv[a_ + 128] + spv[a_ + 192];
            for (int off = 32; off; off >>= 1) v += __shfl_xor(v, off);
            float m = adv;
            for (int off = 32; off; off >>= 1) m += __shfl_xor(m, off);
            m *= (1.f / 64.f);
            out[a_] = (v + bv[0]) + adv - m;
        }
    }
}

extern "C" void kernel_launch(void* const* d_in, const int* in_sizes, int n_in,
                              void* d_out, int out_size, void* d_ws, size_t ws_size,
                              hipStream_t stream) {
    const float* node_x   = (const float*)d_in[0];
    const float* flat_obs = (const float*)d_in[1];
    const float* gcn_w    = (const float*)d_in[2];
    const float* gcn_b    = (const float*)d_in[3];
    const float* w1       = (const float*)d_in[4];
    const float* b1       = (const float*)d_in[5];
    const float* w2       = (const float*)d_in[6];
    const float* b2       = (const float*)d_in[7];
    const float* wv       = (const float*)d_in[8];
    const float* bv       = (const float*)d_in[9];
    const float* wa       = (const float*)d_in[10];
    const float* ba       = (const float*)d_in[11];
    const int*   ei       = (const int*)d_in[12];   // x64 disabled -> int32
    const int* src = ei;
    const int* dst = ei + N_EDGES;

    int* wsi = (int*)d_ws;
    float* out = (float*)d_out;

    // zero barrier state + bucket cursors (16.4 KB)
    hipMemsetAsync(wsi, 0, (2 + N_NODES) * sizeof(int), stream);
    k_fused<<<NBLK, 256, 0, stream>>>(node_x, flat_obs, gcn_w, gcn_b,
                                      w1, b1, w2, b2, wv, bv, wa, ba,
                                      src, dst, wsi, out);
}

// Round 12
// 210.486 us; speedup vs baseline: 3.7838x; 3.7838x over previous
//
#include <hip/hip_runtime.h>

#define N_NODES 4096
#define F_UAV 64
#define NOBS 262400
#define GCN_FLAT (N_NODES * F_UAV)   // 262144
#define HDIM 1024
#define N_ACT 64
#define N_EDGES 65536
#define NBUCKET 64

typedef float f32x4 __attribute__((ext_vector_type(4)));
typedef float f32x2 __attribute__((ext_vector_type(2)));

// ---- workspace layout (4-byte units). cur zeroed by memset (16 KB).
#define OFF_CUR    0                           // 4096 ints (bucket cursor == in-degree)
#define OFF_SSRC   (OFF_CUR + N_NODES)         // 4096*64 ints
#define OFF_H      (OFF_SSRC + N_NODES * NBUCKET)  // 262144 floats
#define OFF_P1     (OFF_H + GCN_FLAT)          // 2048*1024 floats
#define OFF_Q1T    (OFF_P1 + 2048 * HDIM)      // 1024*128 floats
#define OFF_P2     (OFF_Q1T + HDIM * 128)      // 64*1024 floats

// h = node_x @ gcn_w (4096x64 @ 64x64); blocks <256 also bucket-place edges:
// ssrc[d][slot] = src, cur[d] ends as full in-degree (placements beyond
// NBUCKET dropped; P[deg>64] ~ 1e-20 for E/N=16).
__global__ __launch_bounds__(256) void k_gcn_h(const float* __restrict__ nx,
                                               const float* __restrict__ w,
                                               const int* __restrict__ src,
                                               const int* __restrict__ dst,
                                               float* __restrict__ h,
                                               int* __restrict__ cur,
                                               int* __restrict__ ssrc) {
    __shared__ float sw[F_UAV * F_UAV];
    __shared__ float sx4[256];
    int tid = threadIdx.x;
    for (int i = tid; i < F_UAV * F_UAV; i += 256) sw[i] = w[i];
    sx4[tid] = nx[blockIdx.x * 256 + tid];
    if (blockIdx.x < 256) {
        int e = blockIdx.x * 256 + tid;
        int d = dst[e];
        int slot = atomicAdd(&cur[d], 1);
        if (slot < NBUCKET) ssrc[d * NBUCKET + slot] = src[e];
    }
    __syncthreads();
    int r = tid >> 6, j = tid & 63;
    float acc = 0.f;
#pragma unroll
    for (int k = 0; k < F_UAV; ++k) acc += sx4[r * 64 + k] * sw[k * F_UAV + j];
    h[blockIdx.x * 256 + r * 64 + j] = acc;
}

// mv1 with inline GCN gather: block b owns w1 rows [128b,128b+128) = nodes
// {2b, 2b+1} (+ tail row GCN_FLAT+b for b<256). 4 waves: wave w gathers
// neighbors i%2==(w&1) of node 2b+(w>>1) from L2-resident h into LDS (float
// atomics), then all 4 waves stream 512KB of w1 exactly like the validated
// 6.22 TB/s k_matvec.
__global__ __launch_bounds__(256) void k_mv1g(const float* __restrict__ h,
                                              const int* __restrict__ cur,
                                              const int* __restrict__ ssrc,
                                              const float* __restrict__ gb,
                                              const float* __restrict__ obs,
                                              const float* __restrict__ W,
                                              float* __restrict__ part) {
    __shared__ float sxa[128];
    __shared__ float sx[129];
    int tid = threadIdx.x, b = blockIdx.x;
    int w = tid >> 6, l = tid & 63;
    if (tid < 128) sxa[tid] = 0.f;
    __syncthreads();
    {
        int n = 2 * b + (w >> 1);
        int deg = cur[n];
        int dm = deg < NBUCKET ? deg : NBUCKET;
        float a0 = 0.f;
        for (int i = (w & 1); i < dm; i += 2) {
            int s = ssrc[n * NBUCKET + i];
            a0 += h[s * 64 + l] * rsqrtf((float)(cur[s] + 1));
        }
        atomicAdd(&sxa[(w >> 1) * 64 + l], a0);
    }
    __syncthreads();
    if (tid < 128) {
        int nn = 2 * b + (tid >> 6);
        float di = rsqrtf((float)(cur[nn] + 1));
        sx[tid] = di * sxa[tid] + di * di * h[nn * 64 + (tid & 63)] + gb[tid & 63];
    }
    if (tid == 128) sx[128] = (b < 256) ? obs[GCN_FLAT + b] : 0.f;
    __syncthreads();
    f32x4 acc = {0.f, 0.f, 0.f, 0.f};
    const f32x4* Wr = (const f32x4*)W + (size_t)(b * 128) * (HDIM / 4) + tid;
    for (int k = 0; k < 128; k += 8) {
#pragma unroll
        for (int u = 0; u < 8; ++u)
            acc += sx[k + u] * __builtin_nontemporal_load(&Wr[(size_t)(k + u) * (HDIM / 4)]);
    }
    if (b < 256) {
        const f32x4* wt = (const f32x4*)W + (size_t)(GCN_FLAT + b) * (HDIM / 4) + tid;
        acc += sx[128] * __builtin_nontemporal_load(wt);
    }
    ((f32x4*)(part + (size_t)b * HDIM))[tid] = acc;
}

// stage-A: block s sums 16 consecutive partial rows, writes TRANSPOSED qT[j][s]
template <int NSEG>
__global__ __launch_bounds__(256) void k_sum16T(const float* __restrict__ part,
                                                float* __restrict__ qT) {
    int t = threadIdx.x, s = blockIdx.x;
    const f32x4* p = ((const f32x4*)part) + (size_t)s * 16 * (HDIM / 4) + t;
    f32x4 acc = {0.f, 0.f, 0.f, 0.f};
#pragma unroll
    for (int r = 0; r < 16; ++r) acc += p[(size_t)r * (HDIM / 4)];
#pragma unroll
    for (int u = 0; u < 4; ++u) qT[(size_t)(4 * t + u) * NSEG + s] = acc[u];
}

// fused: y1[16b..16b+16) = relu(b1 + rowsum of q1T), then 16-row matvec vs w2.
__global__ __launch_bounds__(256) void k_fin_mv2(const float* __restrict__ q1T,
                                                 const float* __restrict__ b1,
                                                 const float* __restrict__ w2,
                                                 float* __restrict__ p2) {
    __shared__ float s_y[16];
    int t = threadIdx.x, b = blockIdx.x;
    int w = t >> 6, l = t & 63;
#pragma unroll
    for (int rr = 0; rr < 4; ++rr) {
        int j = 16 * b + 4 * w + rr;
        f32x2 v = *(const f32x2*)&q1T[(size_t)j * 128 + 2 * l];
        float sm = v.x + v.y;
        for (int off = 32; off; off >>= 1) sm += __shfl_xor(sm, off);
        if (l == 0) s_y[4 * w + rr] = fmaxf(b1[j] + sm, 0.f);
    }
    __syncthreads();
    f32x4 acc = {0.f, 0.f, 0.f, 0.f};
    const f32x4* Wr = ((const f32x4*)w2) + (size_t)(16 * b) * (HDIM / 4) + t;
#pragma unroll
    for (int i = 0; i < 16; ++i) acc += s_y[i] * Wr[(size_t)i * (HDIM / 4)];
    ((f32x4*)(p2 + (size_t)b * HDIM))[t] = acc;
}

// fused: y2 = relu(b2 + colsum of p2[64][1024]) then dueling heads. 1 block x 1024.
__global__ __launch_bounds__(1024) void k_heads_f(const float* __restrict__ p2,
                                                  const float* __restrict__ b2,
                                                  const float* __restrict__ wv,
                                                  const float* __restrict__ bv,
                                                  const float* __restrict__ wa,
                                                  const float* __restrict__ ba,
                                                  float* __restrict__ out) {
    __shared__ float y2s[1024];
    __shared__ float s_adv[16][64];
    __shared__ float s_pv[1024];
    int t = threadIdx.x;
    float acc = b2[t];
#pragma unroll 8
    for (int s = 0; s < 64; ++s) acc += p2[s * HDIM + t];
    float y = fmaxf(acc, 0.f);
    y2s[t] = y;
    s_pv[t] = y * wv[t];
    __syncthreads();
    int g = t >> 6, a = t & 63;
    float pa = 0.f;
#pragma unroll 4
    for (int kk = 0; kk < 64; ++kk) pa += y2s[g * 64 + kk] * wa[(g * 64 + kk) * 64 + a];
    s_adv[g][a] = pa;
    __syncthreads();
    if (t < 64) {
        float adv = ba[a];
#pragma unroll
        for (int gg = 0; gg < 16; ++gg) adv += s_adv[gg][a];
        float v = 0.f;
#pragma unroll
        for (int i = 0; i < 16; ++i) v += s_pv[a + 64 * i];
        for (int off = 32; off; off >>= 1) v += __shfl_xor(v, off);
        float m = adv;
        for (int off = 32; off; off >>= 1) m += __shfl_xor(m, off);
        m *= (1.f / 64.f);
        out[a] = (v + bv[0]) + adv - m;
    }
}

extern "C" void kernel_launch(void* const* d_in, const int* in_sizes, int n_in,
                              void* d_out, int out_size, void* d_ws, size_t ws_size,
                              hipStream_t stream) {
    const float* node_x   = (const float*)d_in[0];
    const float* flat_obs = (const float*)d_in[1];
    const float* gcn_w    = (const float*)d_in[2];
    const float* gcn_b    = (const float*)d_in[3];
    const float* w1       = (const float*)d_in[4];
    const float* b1       = (const float*)d_in[5];
    const float* w2       = (const float*)d_in[6];
    const float* b2       = (const float*)d_in[7];
    const float* wv       = (const float*)d_in[8];
    const float* bv       = (const float*)d_in[9];
    const float* wa       = (const float*)d_in[10];
    const float* ba       = (const float*)d_in[11];
    const int*   ei       = (const int*)d_in[12];   // x64 disabled -> int32
    const int* src = ei;
    const int* dst = ei + N_EDGES;

    int* wsi = (int*)d_ws;
    float* wsf = (float*)d_ws;
    int*   cur  = wsi + OFF_CUR;
    int*   ssrc = wsi + OFF_SSRC;
    float* h    = wsf + OFF_H;
    float* p1   = wsf + OFF_P1;
    float* q1T  = wsf + OFF_Q1T;
    float* p2   = wsf + OFF_P2;
    float* out  = (float*)d_out;

    hipMemsetAsync(cur, 0, N_NODES * sizeof(int), stream);
    k_gcn_h<<<GCN_FLAT / 256, 256, 0, stream>>>(node_x, gcn_w, src, dst, h, cur, ssrc);
    k_mv1g<<<2048, 256, 0, stream>>>(h, cur, ssrc, gcn_b, flat_obs, w1, p1);
    k_sum16T<128><<<128, 256, 0, stream>>>(p1, q1T);
    k_fin_mv2<<<64, 256, 0, stream>>>(q1T, b1, w2, p2);
    k_heads_f<<<1, 1024, 0, stream>>>(p2, b2, wv, bv, wa, ba, out);
}

// Round 13
// 209.536 us; speedup vs baseline: 3.8009x; 1.0045x over previous
//
#include <hip/hip_runtime.h>

#define N_NODES 4096
#define F_UAV 64
#define NOBS 262400
#define GCN_FLAT (N_NODES * F_UAV)   // 262144
#define HDIM 1024
#define N_ACT 64
#define N_EDGES 65536
#define NBUCKET 64

typedef float f32x4 __attribute__((ext_vector_type(4)));
typedef float f32x2 __attribute__((ext_vector_type(2)));

// ---- workspace layout (4-byte units). cur zeroed by memset (16 KB).
#define OFF_CUR    0                           // 4096 ints (bucket cursor == in-degree)
#define OFF_SSRC   (OFF_CUR + N_NODES)         // 4096*64 ints
#define OFF_P1     (OFF_SSRC + N_NODES * NBUCKET)  // 2048*1024 floats
#define OFF_Q1T    (OFF_P1 + 2048 * HDIM)      // 1024*128 floats
#define OFF_P2     (OFF_Q1T + HDIM * 128)      // 64*1024 floats

// bucket-place edges: ssrc[d][slot] = src; cur[d] ends as full in-degree
// (placements beyond NBUCKET dropped; P[deg>64] ~ 1e-20 for E/N=16).
__global__ __launch_bounds__(256) void k_place(const int* __restrict__ src,
                                               const int* __restrict__ dst,
                                               int* __restrict__ cur,
                                               int* __restrict__ ssrc) {
    int e = blockIdx.x * 256 + threadIdx.x;
    int d = dst[e];
    int slot = atomicAdd(&cur[d], 1);
    if (slot < NBUCKET) ssrc[d * NBUCKET + slot] = src[e];
}

// mv1 with inline COMMUTED GCN: block b owns w1 rows [128b,128b+128) = nodes
// {2b,2b+1} (+ tail row GCN_FLAT+b for b<256). Since GCN is linear,
// x[n] = (dinv[n]*sum_s dinv[s]*nx[s] + dinv[n]^2*nx[n]) @ gcn_w + gb.
// Gather raw nx rows (L2), apply 64x64 gcn_w from LDS, then stream w1
// exactly like the validated 6.22 TB/s k_matvec.
__global__ __launch_bounds__(256) void k_mv1g(const float* __restrict__ nx,
                                              const int* __restrict__ cur,
                                              const int* __restrict__ ssrc,
                                              const float* __restrict__ gw,
                                              const float* __restrict__ gb,
                                              const float* __restrict__ obs,
                                              const float* __restrict__ W,
                                              float* __restrict__ part) {
    __shared__ float sgw[F_UAV * F_UAV];   // 16 KB
    __shared__ float sv[128];              // aggregated input rows (2 nodes)
    __shared__ float sx[129];              // x rows ready for streaming
    int tid = threadIdx.x, b = blockIdx.x;
    int w = tid >> 6, l = tid & 63;
    for (int i = tid; i < F_UAV * F_UAV; i += 256) sgw[i] = gw[i];
    if (tid < 128) sv[tid] = 0.f;
    __syncthreads();
    // gather neighbors of node n = 2b + (w>>1), parity w&1
    {
        int n = 2 * b + (w >> 1);
        int deg = cur[n];
        int dm = deg < NBUCKET ? deg : NBUCKET;
        float a0 = 0.f;
        for (int i = (w & 1); i < dm; i += 2) {
            int s = ssrc[n * NBUCKET + i];
            a0 += nx[s * 64 + l] * rsqrtf((float)(cur[s] + 1));
        }
        atomicAdd(&sv[(w >> 1) * 64 + l], a0);
    }
    __syncthreads();
    // finalize aggregated row: sv[n][k] = dinv*agg + dinv^2*nx[n][k]
    if (tid < 128) {
        int n = 2 * b + (tid >> 6);
        float di = rsqrtf((float)(cur[n] + 1));
        sv[tid] = di * sv[tid] + di * di * nx[n * 64 + (tid & 63)];
    }
    __syncthreads();
    // x rows = sv @ gcn_w + gb (128 threads: node q = t>>6, col j = t&63)
    if (tid < 128) {
        int q = tid >> 6, j = tid & 63;
        float xv = gb[j];
#pragma unroll 8
        for (int k = 0; k < 64; ++k) xv += sv[q * 64 + k] * sgw[k * 64 + j];
        sx[tid] = xv;
    }
    if (tid == 128) sx[128] = (b < 256) ? obs[GCN_FLAT + b] : 0.f;
    __syncthreads();
    // stream 512 KB of w1
    f32x4 acc = {0.f, 0.f, 0.f, 0.f};
    const f32x4* Wr = (const f32x4*)W + (size_t)(b * 128) * (HDIM / 4) + tid;
    for (int k = 0; k < 128; k += 8) {
#pragma unroll
        for (int u = 0; u < 8; ++u)
            acc += sx[k + u] * __builtin_nontemporal_load(&Wr[(size_t)(k + u) * (HDIM / 4)]);
    }
    if (b < 256) {
        const f32x4* wt = (const f32x4*)W + (size_t)(GCN_FLAT + b) * (HDIM / 4) + tid;
        acc += sx[128] * __builtin_nontemporal_load(wt);
    }
    ((f32x4*)(part + (size_t)b * HDIM))[tid] = acc;
}

// stage-A: block s sums 16 consecutive partial rows, writes TRANSPOSED qT[j][s]
template <int NSEG>
__global__ __launch_bounds__(256) void k_sum16T(const float* __restrict__ part,
                                                float* __restrict__ qT) {
    int t = threadIdx.x, s = blockIdx.x;
    const f32x4* p = ((const f32x4*)part) + (size_t)s * 16 * (HDIM / 4) + t;
    f32x4 acc = {0.f, 0.f, 0.f, 0.f};
#pragma unroll
    for (int r = 0; r < 16; ++r) acc += p[(size_t)r * (HDIM / 4)];
#pragma unroll
    for (int u = 0; u < 4; ++u) qT[(size_t)(4 * t + u) * NSEG + s] = acc[u];
}

// fused: y1[16b..16b+16) = relu(b1 + rowsum of q1T), then 16-row matvec vs w2.
__global__ __launch_bounds__(256) void k_fin_mv2(const float* __restrict__ q1T,
                                                 const float* __restrict__ b1,
                                                 const float* __restrict__ w2,
                                                 float* __restrict__ p2) {
    __shared__ float s_y[16];
    int t = threadIdx.x, b = blockIdx.x;
    int w = t >> 6, l = t & 63;
#pragma unroll
    for (int rr = 0; rr < 4; ++rr) {
        int j = 16 * b + 4 * w + rr;
        f32x2 v = *(const f32x2*)&q1T[(size_t)j * 128 + 2 * l];
        float sm = v.x + v.y;
        for (int off = 32; off; off >>= 1) sm += __shfl_xor(sm, off);
        if (l == 0) s_y[4 * w + rr] = fmaxf(b1[j] + sm, 0.f);
    }
    __syncthreads();
    f32x4 acc = {0.f, 0.f, 0.f, 0.f};
    const f32x4* Wr = ((const f32x4*)w2) + (size_t)(16 * b) * (HDIM / 4) + t;
#pragma unroll
    for (int i = 0; i < 16; ++i) acc += s_y[i] * Wr[(size_t)i * (HDIM / 4)];
    ((f32x4*)(p2 + (size_t)b * HDIM))[t] = acc;
}

// fused: y2 = relu(b2 + colsum of p2[64][1024]) then dueling heads. 1 block x 1024.
__global__ __launch_bounds__(1024) void k_heads_f(const float* __restrict__ p2,
                                                  const float* __restrict__ b2,
                                                  const float* __restrict__ wv,
                                                  const float* __restrict__ bv,
                                                  const float* __restrict__ wa,
                                                  const float* __restrict__ ba,
                                                  float* __restrict__ out) {
    __shared__ float y2s[1024];
    __shared__ float s_adv[16][64];
    __shared__ float s_pv[1024];
    int t = threadIdx.x;
    float acc = b2[t];
#pragma unroll 8
    for (int s = 0; s < 64; ++s) acc += p2[s * HDIM + t];
    float y = fmaxf(acc, 0.f);
    y2s[t] = y;
    s_pv[t] = y * wv[t];
    __syncthreads();
    int g = t >> 6, a = t & 63;
    float pa = 0.f;
#pragma unroll 4
    for (int kk = 0; kk < 64; ++kk) pa += y2s[g * 64 + kk] * wa[(g * 64 + kk) * 64 + a];
    s_adv[g][a] = pa;
    __syncthreads();
    if (t < 64) {
        float adv = ba[a];
#pragma unroll
        for (int gg = 0; gg < 16; ++gg) adv += s_adv[gg][a];
        float v = 0.f;
#pragma unroll
        for (int i = 0; i < 16; ++i) v += s_pv[a + 64 * i];
        for (int off = 32; off; off >>= 1) v += __shfl_xor(v, off);
        float m = adv;
        for (int off = 32; off; off >>= 1) m += __shfl_xor(m, off);
        m *= (1.f / 64.f);
        out[a] = (v + bv[0]) + adv - m;
    }
}

extern "C" void kernel_launch(void* const* d_in, const int* in_sizes, int n_in,
                              void* d_out, int out_size, void* d_ws, size_t ws_size,
                              hipStream_t stream) {
    const float* node_x   = (const float*)d_in[0];
    const float* flat_obs = (const float*)d_in[1];
    const float* gcn_w    = (const float*)d_in[2];
    const float* gcn_b    = (const float*)d_in[3];
    const float* w1       = (const float*)d_in[4];
    const float* b1       = (const float*)d_in[5];
    const float* w2       = (const float*)d_in[6];
    const float* b2       = (const float*)d_in[7];
    const float* wv       = (const float*)d_in[8];
    const float* bv       = (const float*)d_in[9];
    const float* wa       = (const float*)d_in[10];
    const float* ba       = (const float*)d_in[11];
    const int*   ei       = (const int*)d_in[12];   // x64 disabled -> int32
    const int* src = ei;
    const int* dst = ei + N_EDGES;

    int* wsi = (int*)d_ws;
    float* wsf = (float*)d_ws;
    int*   cur  = wsi + OFF_CUR;
    int*   ssrc = wsi + OFF_SSRC;
    float* p1   = wsf + OFF_P1;
    float* q1T  = wsf + OFF_Q1T;
    float* p2   = wsf + OFF_P2;
    float* out  = (float*)d_out;

    hipMemsetAsync(cur, 0, N_NODES * sizeof(int), stream);
    k_place<<<N_EDGES / 256, 256, 0, stream>>>(src, dst, cur, ssrc);
    k_mv1g<<<2048, 256, 0, stream>>>(node_x, cur, ssrc, gcn_w, gcn_b,
                                     flat_obs, w1, p1);
    k_sum16T<128><<<128, 256, 0, stream>>>(p1, q1T);
    k_fin_mv2<<<64, 256, 0, stream>>>(q1T, b1, w2, p2);
    k_heads_f<<<1, 1024, 0, stream>>>(p2, b2, wv, bv, wa, ba, out);
}

// Round 14
// 208.962 us; speedup vs baseline: 3.8114x; 1.0027x over previous
//
#include <hip/hip_runtime.h>

#define N_NODES 4096
#define F_UAV 64
#define NOBS 262400
#define GCN_FLAT (N_NODES * F_UAV)   // 262144
#define HDIM 1024
#define N_ACT 64
#define N_EDGES 65536
#define NBUCKET 64

typedef float f32x4 __attribute__((ext_vector_type(4)));
typedef float f32x2 __attribute__((ext_vector_type(2)));

// ---- workspace layout (4-byte units). cur zeroed by memset (16 KB).
#define OFF_CUR    0                           // 4096 ints (bucket cursor == in-degree)
#define OFF_SSRC   (OFF_CUR + N_NODES)         // 4096*64 ints
#define OFF_P1     (OFF_SSRC + N_NODES * NBUCKET)  // 2048*1024 floats
#define OFF_Q1T    (OFF_P1 + 2048 * HDIM)      // 1024*128 floats
#define OFF_P2     (OFF_Q1T + HDIM * 128)      // 64*1024 floats

// bucket-place edges: ssrc[d][slot] = src; cur[d] ends as full in-degree
// (placements beyond NBUCKET dropped; P[deg>64] ~ 1e-20 for E/N=16).
__global__ __launch_bounds__(256) void k_place(const int* __restrict__ src,
                                               const int* __restrict__ dst,
                                               int* __restrict__ cur,
                                               int* __restrict__ ssrc) {
    int e = blockIdx.x * 256 + threadIdx.x;
    int d = dst[e];
    int slot = atomicAdd(&cur[d], 1);
    if (slot < NBUCKET) ssrc[d * NBUCKET + slot] = src[e];
}

// mv1 with inline COMMUTED GCN: block b owns w1 rows [128b,128b+128) = nodes
// {2b,2b+1} (+ tail row GCN_FLAT+b for b<256).
// Gather uses a FIXED-TRIP masked loop (32 per parity, unroll-8) so the
// ssrc->cur->nx load chain pipelines instead of serializing (~8x latency cut).
__global__ __launch_bounds__(256) void k_mv1g(const float* __restrict__ nx,
                                              const int* __restrict__ cur,
                                              const int* __restrict__ ssrc,
                                              const float* __restrict__ gw,
                                              const float* __restrict__ gb,
                                              const float* __restrict__ obs,
                                              const float* __restrict__ W,
                                              float* __restrict__ part) {
    __shared__ float sgw[F_UAV * F_UAV];   // 16 KB
    __shared__ float sv[128];              // aggregated input rows (2 nodes)
    __shared__ float sx[129];              // x rows ready for streaming
    int tid = threadIdx.x, b = blockIdx.x;
    int w = tid >> 6, l = tid & 63;
    for (int i = tid; i < F_UAV * F_UAV; i += 256) sgw[i] = gw[i];
    if (tid < 128) sv[tid] = 0.f;
    __syncthreads();
    // gather neighbors of node n = 2b + (w>>1), parity w&1, fixed-trip masked
    {
        int n = 2 * b + (w >> 1);
        int deg = cur[n];
        int dm = deg < NBUCKET ? deg : NBUCKET;
        const int* bucket = ssrc + n * NBUCKET;
        float a0 = 0.f;
#pragma unroll 8
        for (int i2 = 0; i2 < NBUCKET / 2; ++i2) {
            int i = 2 * i2 + (w & 1);
            bool valid = (i < dm);
            int s = bucket[i];               // always in-bounds (bucket array)
            int sf = valid ? s : 0;          // clamp masked lanes to node 0
            float c = nx[sf * 64 + l] * rsqrtf((float)(cur[sf] + 1));
            a0 += valid ? c : 0.f;
        }
        atomicAdd(&sv[(w >> 1) * 64 + l], a0);
    }
    __syncthreads();
    // finalize aggregated row: sv[n][k] = dinv*agg + dinv^2*nx[n][k]
    if (tid < 128) {
        int n = 2 * b + (tid >> 6);
        float di = rsqrtf((float)(cur[n] + 1));
        sv[tid] = di * sv[tid] + di * di * nx[n * 64 + (tid & 63)];
    }
    __syncthreads();
    // x rows = sv @ gcn_w + gb (128 threads: node q = t>>6, col j = t&63)
    if (tid < 128) {
        int q = tid >> 6, j = tid & 63;
        float xv = gb[j];
#pragma unroll 8
        for (int k = 0; k < 64; ++k) xv += sv[q * 64 + k] * sgw[k * 64 + j];
        sx[tid] = xv;
    }
    if (tid == 128) sx[128] = (b < 256) ? obs[GCN_FLAT + b] : 0.f;
    __syncthreads();
    // stream 512 KB of w1
    f32x4 acc = {0.f, 0.f, 0.f, 0.f};
    const f32x4* Wr = (const f32x4*)W + (size_t)(b * 128) * (HDIM / 4) + tid;
    for (int k = 0; k < 128; k += 8) {
#pragma unroll
        for (int u = 0; u < 8; ++u)
            acc += sx[k + u] * __builtin_nontemporal_load(&Wr[(size_t)(k + u) * (HDIM / 4)]);
    }
    if (b < 256) {
        const f32x4* wt = (const f32x4*)W + (size_t)(GCN_FLAT + b) * (HDIM / 4) + tid;
        acc += sx[128] * __builtin_nontemporal_load(wt);
    }
    ((f32x4*)(part + (size_t)b * HDIM))[tid] = acc;
}

// stage-A: block s sums 16 consecutive partial rows, writes TRANSPOSED qT[j][s]
template <int NSEG>
__global__ __launch_bounds__(256) void k_sum16T(const float* __restrict__ part,
                                                float* __restrict__ qT) {
    int t = threadIdx.x, s = blockIdx.x;
    const f32x4* p = ((const f32x4*)part) + (size_t)s * 16 * (HDIM / 4) + t;
    f32x4 acc = {0.f, 0.f, 0.f, 0.f};
#pragma unroll
    for (int r = 0; r < 16; ++r) acc += p[(size_t)r * (HDIM / 4)];
#pragma unroll
    for (int u = 0; u < 4; ++u) qT[(size_t)(4 * t + u) * NSEG + s] = acc[u];
}

// fused: y1[16b..16b+16) = relu(b1 + rowsum of q1T), then 16-row matvec vs w2.
__global__ __launch_bounds__(256) void k_fin_mv2(const float* __restrict__ q1T,
                                                 const float* __restrict__ b1,
                                                 const float* __restrict__ w2,
                                                 float* __restrict__ p2) {
    __shared__ float s_y[16];
    int t = threadIdx.x, b = blockIdx.x;
    int w = t >> 6, l = t & 63;
#pragma unroll
    for (int rr = 0; rr < 4; ++rr) {
        int j = 16 * b + 4 * w + rr;
        f32x2 v = *(const f32x2*)&q1T[(size_t)j * 128 + 2 * l];
        float sm = v.x + v.y;
        for (int off = 32; off; off >>= 1) sm += __shfl_xor(sm, off);
        if (l == 0) s_y[4 * w + rr] = fmaxf(b1[j] + sm, 0.f);
    }
    __syncthreads();
    f32x4 acc = {0.f, 0.f, 0.f, 0.f};
    const f32x4* Wr = ((const f32x4*)w2) + (size_t)(16 * b) * (HDIM / 4) + t;
#pragma unroll
    for (int i = 0; i < 16; ++i) acc += s_y[i] * Wr[(size_t)i * (HDIM / 4)];
    ((f32x4*)(p2 + (size_t)b * HDIM))[t] = acc;
}

// fused: y2 = relu(b2 + colsum of p2[64][1024]) then dueling heads. 1 block x 1024.
__global__ __launch_bounds__(1024) void k_heads_f(const float* __restrict__ p2,
                                                  const float* __restrict__ b2,
                                                  const float* __restrict__ wv,
                                                  const float* __restrict__ bv,
                                                  const float* __restrict__ wa,
                                                  const float* __restrict__ ba,
                                                  float* __restrict__ out) {
    __shared__ float y2s[1024];
    __shared__ float s_adv[16][64];
    __shared__ float s_pv[1024];
    int t = threadIdx.x;
    float acc = b2[t];
#pragma unroll 8
    for (int s = 0; s < 64; ++s) acc += p2[s * HDIM + t];
    float y = fmaxf(acc, 0.f);
    y2s[t] = y;
    s_pv[t] = y * wv[t];
    __syncthreads();
    int g = t >> 6, a = t & 63;
    float pa = 0.f;
#pragma unroll 4
    for (int kk = 0; kk < 64; ++kk) pa += y2s[g * 64 + kk] * wa[(g * 64 + kk) * 64 + a];
    s_adv[g][a] = pa;
    __syncthreads();
    if (t < 64) {
        float adv = ba[a];
#pragma unroll
        for (int gg = 0; gg < 16; ++gg) adv += s_adv[gg][a];
        float v = 0.f;
#pragma unroll
        for (int i = 0; i < 16; ++i) v += s_pv[a + 64 * i];
        for (int off = 32; off; off >>= 1) v += __shfl_xor(v, off);
        float m = adv;
        for (int off = 32; off; off >>= 1) m += __shfl_xor(m, off);
        m *= (1.f / 64.f);
        out[a] = (v + bv[0]) + adv - m;
    }
}

extern "C" void kernel_launch(void* const* d_in, const int* in_sizes, int n_in,
                              void* d_out, int out_size, void* d_ws, size_t ws_size,
                              hipStream_t stream) {
    const float* node_x   = (const float*)d_in[0];
    const float* flat_obs = (const float*)d_in[1];
    const float* gcn_w    = (const float*)d_in[2];
    const float* gcn_b    = (const float*)d_in[3];
    const float* w1       = (const float*)d_in[4];
    const float* b1       = (const float*)d_in[5];
    const float* w2       = (const float*)d_in[6];
    const float* b2       = (const float*)d_in[7];
    const float* wv       = (const float*)d_in[8];
    const float* bv       = (const float*)d_in[9];
    const float* wa       = (const float*)d_in[10];
    const float* ba       = (const float*)d_in[11];
    const int*   ei       = (const int*)d_in[12];   // x64 disabled -> int32
    const int* src = ei;
    const int* dst = ei + N_EDGES;

    int* wsi = (int*)d_ws;
    float* wsf = (float*)d_ws;
    int*   cur  = wsi + OFF_CUR;
    int*   ssrc = wsi + OFF_SSRC;
    float* p1   = wsf + OFF_P1;
    float* q1T  = wsf + OFF_Q1T;
    float* p2   = wsf + OFF_P2;
    float* out  = (float*)d_out;

    hipMemsetAsync(cur, 0, N_NODES * sizeof(int), stream);
    k_place<<<N_EDGES / 256, 256, 0, stream>>>(src, dst, cur, ssrc);
    k_mv1g<<<2048, 256, 0, stream>>>(node_x, cur, ssrc, gcn_w, gcn_b,
                                     flat_obs, w1, p1);
    k_sum16T<128><<<128, 256, 0, stream>>>(p1, q1T);
    k_fin_mv2<<<64, 256, 0, stream>>>(q1T, b1, w2, p2);
    k_heads_f<<<1, 1024, 0, stream>>>(p2, b2, wv, bv, wa, ba, out);
}